// Round 1
// baseline (1590.650 us; speedup 1.0000x reference)
//
#include <hip/hip_runtime.h>
#include <cstddef>

#define NN 50000
#define NR 8
#define NE 800000
#define DD 128
#define XPAD 132   // padded LDS row stride (floats): 16B-aligned rows, conflict-spread columns

// ---------------------------------------------------------------------------
// Transform: for blockIdx.y + y_off == r < 8:  H[r] = X @ W[r]   (into ws)
//            for r == 8:                       out  = X @ W0
// block = 256 threads; tile = 64 nodes x 128 outs; thread tile = 8 nodes x 4 outs
// ---------------------------------------------------------------------------
__global__ __launch_bounds__(256) void xform_kernel(
    const float* __restrict__ X, const float* __restrict__ W,
    const float* __restrict__ W0, float* __restrict__ H, float* __restrict__ out,
    int y_off)
{
    __shared__ float Xs[64][XPAD];   // row-major node x feat, padded

    const int r  = blockIdx.y + y_off;
    const int n0 = blockIdx.x * 64;
    const float* __restrict__ Wr  = (r == NR) ? W0 : (W + (size_t)r * DD * DD);
    float* __restrict__ Dst       = (r == NR) ? out : (H + (size_t)r * NN * DD);

    const int tid = threadIdx.x;

    // cooperative load of X tile (64 nodes x 128 feats), coalesced float4
    for (int t = tid; t < 64 * (DD / 4); t += 256) {
        const int row = t >> 5;       // node row 0..63
        const int c4  = t & 31;       // float4 column 0..31
        const int n   = n0 + row;
        float4 v = make_float4(0.f, 0.f, 0.f, 0.f);
        if (n < NN) v = ((const float4*)(X + (size_t)n * DD))[c4];
        Xs[row][c4 * 4 + 0] = v.x;
        Xs[row][c4 * 4 + 1] = v.y;
        Xs[row][c4 * 4 + 2] = v.z;
        Xs[row][c4 * 4 + 3] = v.w;
    }
    __syncthreads();

    const int to = tid & 31;   // out group: columns to*4 .. to*4+3
    const int tn = tid >> 5;   // node group: rows tn*8 .. tn*8+7

    float acc[8][4];
    #pragma unroll
    for (int k = 0; k < 8; ++k)
        #pragma unroll
        for (int j = 0; j < 4; ++j) acc[k][j] = 0.f;

    #pragma unroll 2
    for (int i = 0; i < DD; ++i) {
        const float4 w = ((const float4*)(Wr + i * DD))[to];
        float xs[8];
        #pragma unroll
        for (int k = 0; k < 8; ++k) xs[k] = Xs[tn * 8 + k][i];
        #pragma unroll
        for (int k = 0; k < 8; ++k) {
            acc[k][0] += xs[k] * w.x;
            acc[k][1] += xs[k] * w.y;
            acc[k][2] += xs[k] * w.z;
            acc[k][3] += xs[k] * w.w;
        }
    }

    #pragma unroll
    for (int k = 0; k < 8; ++k) {
        const int n = n0 + tn * 8 + k;
        if (n < NN) {
            float4 v = make_float4(acc[k][0], acc[k][1], acc[k][2], acc[k][3]);
            ((float4*)(Dst + (size_t)n * DD))[to] = v;
        }
    }
}

// ---------------------------------------------------------------------------
// Edge scatter: out[dst] += inv_norm[dst,rel] * H[rel, src, :]
// one 32-lane group per edge, float4 per lane, fp32 HW atomics
// ---------------------------------------------------------------------------
__global__ __launch_bounds__(256) void edge_kernel(
    const float* __restrict__ H, const float* __restrict__ inv_norm,
    const int* __restrict__ src, const int* __restrict__ dst,
    const int* __restrict__ rel, float* __restrict__ out)
{
    const int lane  = threadIdx.x & 31;
    int slot        = (int)((blockIdx.x * blockDim.x + threadIdx.x) >> 5);
    const int nslot = (int)((gridDim.x * blockDim.x) >> 5);

    for (int e = slot; e < NE; e += nslot) {
        const int s = src[e];
        const int d = dst[e];
        const int r = rel[e];
        const float inv = inv_norm[(size_t)d * NR + r];
        const float4 h = ((const float4*)(H + ((size_t)r * NN + s) * DD))[lane];
        float* op = out + (size_t)d * DD + (size_t)lane * 4;
        unsafeAtomicAdd(op + 0, h.x * inv);
        unsafeAtomicAdd(op + 1, h.y * inv);
        unsafeAtomicAdd(op + 2, h.z * inv);
        unsafeAtomicAdd(op + 3, h.w * inv);
    }
}

// ---------------------------------------------------------------------------
// Fallback (ws too small): per-edge on-the-fly transform
// ---------------------------------------------------------------------------
__global__ __launch_bounds__(128) void edge_fallback_kernel(
    const float* __restrict__ X, const float* __restrict__ W,
    const float* __restrict__ inv_norm,
    const int* __restrict__ src, const int* __restrict__ dst,
    const int* __restrict__ rel, float* __restrict__ out)
{
    const int o = threadIdx.x;   // 0..127
    for (int e = blockIdx.x; e < NE; e += gridDim.x) {
        const int s = src[e];
        const int d = dst[e];
        const int r = rel[e];
        const float inv = inv_norm[(size_t)d * NR + r];
        const float* Xr = X + (size_t)s * DD;
        const float* Wr = W + (size_t)r * DD * DD;
        float a = 0.f;
        for (int i = 0; i < DD; ++i) a += Xr[i] * Wr[i * DD + o];
        unsafeAtomicAdd(out + (size_t)d * DD + o, a * inv);
    }
}

extern "C" void kernel_launch(void* const* d_in, const int* in_sizes, int n_in,
                              void* d_out, int out_size, void* d_ws, size_t ws_size,
                              hipStream_t stream)
{
    const float* X        = (const float*)d_in[0];
    const float* W        = (const float*)d_in[1];
    const float* W0       = (const float*)d_in[2];
    const float* inv_norm = (const float*)d_in[3];
    const int*   src      = (const int*)d_in[4];
    const int*   dst      = (const int*)d_in[5];
    const int*   rel      = (const int*)d_in[6];
    float* out = (float*)d_out;
    float* H   = (float*)d_ws;

    const size_t need = (size_t)NR * NN * DD * sizeof(float);
    const int nblk_x = (NN + 63) / 64;

    if (ws_size >= need) {
        // out = X@W0 and H[r] = X@W[r] in one launch (y==8 -> W0 path)
        dim3 grid(nblk_x, NR + 1);
        xform_kernel<<<grid, dim3(256), 0, stream>>>(X, W, W0, H, out, 0);
        edge_kernel<<<2048, 256, 0, stream>>>(H, inv_norm, src, dst, rel, out);
    } else {
        dim3 grid(nblk_x, 1);
        xform_kernel<<<grid, dim3(256), 0, stream>>>(X, W, W0, H, out, NR);
        edge_fallback_kernel<<<8192, 128, 0, stream>>>(X, W, inv_norm, src, dst, rel, out);
    }
}

// Round 2
// 614.616 us; speedup vs baseline: 2.5880x; 2.5880x over previous
//
#include <hip/hip_runtime.h>
#include <hip/hip_bf16.h>
#include <cstddef>

#define NN 50000
#define NR 8
#define NE 800000
#define DD 128
#define KTOT 1024          // NR * DD
#define XPAD 136           // LDS row stride in floats: 544B, 16B-aligned

// ---------------------------------------------------------------------------
// Phase A: counting sort of edges by dst
// ---------------------------------------------------------------------------
__global__ __launch_bounds__(256) void hist_kernel(
    const int* __restrict__ dst, int* __restrict__ cnt)
{
    int e = blockIdx.x * 256 + threadIdx.x;
    if (e < NE) atomicAdd(&cnt[dst[e]], 1);
}

__global__ __launch_bounds__(1024) void scan_kernel(
    const int* __restrict__ cnt, int* __restrict__ offsets, int* __restrict__ cursor)
{
    __shared__ int part[1024];
    const int t = threadIdx.x;
    const int chunk = (NN + 1023) / 1024;           // 49
    const int beg = t * chunk;
    const int end = min(beg + chunk, NN);

    int s = 0;
    for (int i = beg; i < end; ++i) s += cnt[i];
    part[t] = s;
    __syncthreads();
    // inclusive scan (Hillis-Steele)
    for (int off = 1; off < 1024; off <<= 1) {
        int v = (t >= off) ? part[t - off] : 0;
        __syncthreads();
        part[t] += v;
        __syncthreads();
    }
    int run = (t > 0) ? part[t - 1] : 0;            // exclusive base
    for (int i = beg; i < end; ++i) {
        offsets[i] = run;
        cursor[i]  = run;
        run += cnt[i];
    }
    if (t == 1023) offsets[NN] = part[1023];
}

__global__ __launch_bounds__(256) void scatter_kernel(
    const int* __restrict__ src, const int* __restrict__ dst,
    const int* __restrict__ rel, int* __restrict__ cursor,
    unsigned* __restrict__ packed)
{
    int e = blockIdx.x * 256 + threadIdx.x;
    if (e < NE) {
        const int d = dst[e];
        const int pos = atomicAdd(&cursor[d], 1);
        packed[pos] = ((unsigned)rel[e] << 16) | (unsigned)src[e];  // src < 65536
    }
}

// ---------------------------------------------------------------------------
// Phase B: per-node aggregation in X-space.  One wave (64 lanes) per node.
// A[n][r*128 + :] = inv_norm[n,r] * sum_{edges e: dst=n, rel=r} X[src[e], :]
// A stored bf16.
// ---------------------------------------------------------------------------
__global__ __launch_bounds__(256) void agg_kernel(
    const float* __restrict__ X, const float* __restrict__ inv_norm,
    const int* __restrict__ offsets, const unsigned* __restrict__ packed,
    __hip_bfloat16* __restrict__ A)
{
    const int lane = threadIdx.x & 63;
    const int node = blockIdx.x * 4 + (threadIdx.x >> 6);
    if (node >= NN) return;

    const int beg = offsets[node];
    const int end = offsets[node + 1];

    float2 a[NR];
    #pragma unroll
    for (int r = 0; r < NR; ++r) { a[r].x = 0.f; a[r].y = 0.f; }

    for (int e = beg; e < end; ++e) {
        const unsigned p = packed[e];                 // wave-uniform
        const int s = (int)(p & 0xFFFFu);
        const int r = (int)(p >> 16);
        const float2 x = ((const float2*)(X + (size_t)s * DD))[lane];
        #pragma unroll
        for (int rr = 0; rr < NR; ++rr) {
            if (rr == r) { a[rr].x += x.x; a[rr].y += x.y; }
        }
    }

    __hip_bfloat16* An = A + (size_t)node * KTOT;
    #pragma unroll
    for (int rr = 0; rr < NR; ++rr) {
        const float inv = inv_norm[(size_t)node * NR + rr];
        __hip_bfloat162 h;
        h.x = __float2bfloat16(a[rr].x * inv);
        h.y = __float2bfloat16(a[rr].y * inv);
        ((__hip_bfloat162*)(An + rr * DD))[lane] = h;
    }
}

// ---------------------------------------------------------------------------
// Phase C: out = A (NN x 1024, bf16) @ W (1024 x 128) + X @ W0
// 64-node tile, 256 threads, thread tile = 4 nodes x 8 outs
// ---------------------------------------------------------------------------
__global__ __launch_bounds__(256) void gemm_kernel(
    const __hip_bfloat16* __restrict__ A, const float* __restrict__ X,
    const float* __restrict__ W, const float* __restrict__ W0,
    float* __restrict__ out)
{
    __shared__ __align__(16) float Xs[64][XPAD];

    const int n0  = blockIdx.x * 64;
    const int tid = threadIdx.x;
    const int to  = tid & 15;    // out group: cols to*8 .. to*8+7
    const int tn  = tid >> 4;    // node group: rows tn*4 .. tn*4+3

    float acc[4][8];
    #pragma unroll
    for (int k = 0; k < 4; ++k)
        #pragma unroll
        for (int j = 0; j < 8; ++j) acc[k][j] = 0.f;

    for (int c = 0; c < NR + 1; ++c) {
        // ---- stage 64 x 128 chunk into LDS (fp32) ----
        if (c < NR) {
            for (int t = tid; t < 64 * 32; t += 256) {
                const int row = t >> 5, g = t & 31;
                const int n = n0 + row;
                float4 v = make_float4(0.f, 0.f, 0.f, 0.f);
                if (n < NN) {
                    const __hip_bfloat162* p =
                        (const __hip_bfloat162*)(A + (size_t)n * KTOT + c * DD);
                    const __hip_bfloat162 h0 = p[g * 2];
                    const __hip_bfloat162 h1 = p[g * 2 + 1];
                    v = make_float4(__bfloat162float(h0.x), __bfloat162float(h0.y),
                                    __bfloat162float(h1.x), __bfloat162float(h1.y));
                }
                *(float4*)&Xs[row][g * 4] = v;
            }
        } else {
            for (int t = tid; t < 64 * 32; t += 256) {
                const int row = t >> 5, g = t & 31;
                const int n = n0 + row;
                float4 v = make_float4(0.f, 0.f, 0.f, 0.f);
                if (n < NN) v = ((const float4*)(X + (size_t)n * DD))[g];
                *(float4*)&Xs[row][g * 4] = v;
            }
        }
        __syncthreads();

        const float* __restrict__ Wc = (c < NR) ? (W + (size_t)c * DD * DD) : W0;

        for (int i = 0; i < DD; i += 4) {
            float4 wa[4], wb[4];
            #pragma unroll
            for (int ii = 0; ii < 4; ++ii) {
                wa[ii] = ((const float4*)(Wc + (size_t)(i + ii) * DD))[to * 2];
                wb[ii] = ((const float4*)(Wc + (size_t)(i + ii) * DD))[to * 2 + 1];
            }
            #pragma unroll
            for (int k = 0; k < 4; ++k) {
                const float4 xv = *(const float4*)&Xs[tn * 4 + k][i];
                acc[k][0] += xv.x * wa[0].x + xv.y * wa[1].x + xv.z * wa[2].x + xv.w * wa[3].x;
                acc[k][1] += xv.x * wa[0].y + xv.y * wa[1].y + xv.z * wa[2].y + xv.w * wa[3].y;
                acc[k][2] += xv.x * wa[0].z + xv.y * wa[1].z + xv.z * wa[2].z + xv.w * wa[3].z;
                acc[k][3] += xv.x * wa[0].w + xv.y * wa[1].w + xv.z * wa[2].w + xv.w * wa[3].w;
                acc[k][4] += xv.x * wb[0].x + xv.y * wb[1].x + xv.z * wb[2].x + xv.w * wb[3].x;
                acc[k][5] += xv.x * wb[0].y + xv.y * wb[1].y + xv.z * wb[2].y + xv.w * wb[3].y;
                acc[k][6] += xv.x * wb[0].z + xv.y * wb[1].z + xv.z * wb[2].z + xv.w * wb[3].z;
                acc[k][7] += xv.x * wb[0].w + xv.y * wb[1].w + xv.z * wb[2].w + xv.w * wb[3].w;
            }
        }
        __syncthreads();
    }

    #pragma unroll
    for (int k = 0; k < 4; ++k) {
        const int n = n0 + tn * 4 + k;
        if (n < NN) {
            float4 lo = make_float4(acc[k][0], acc[k][1], acc[k][2], acc[k][3]);
            float4 hi = make_float4(acc[k][4], acc[k][5], acc[k][6], acc[k][7]);
            ((float4*)(out + (size_t)n * DD))[to * 2]     = lo;
            ((float4*)(out + (size_t)n * DD))[to * 2 + 1] = hi;
        }
    }
}

// ---------------------------------------------------------------------------
// Fallback (ws too small): per-edge on-the-fly transform with atomics
// ---------------------------------------------------------------------------
__global__ __launch_bounds__(256) void xform0_kernel(
    const float* __restrict__ X, const float* __restrict__ W0, float* __restrict__ out)
{
    __shared__ __align__(16) float Xs[64][XPAD];
    const int n0 = blockIdx.x * 64;
    const int tid = threadIdx.x;
    for (int t = tid; t < 64 * 32; t += 256) {
        const int row = t >> 5, g = t & 31;
        const int n = n0 + row;
        float4 v = make_float4(0.f, 0.f, 0.f, 0.f);
        if (n < NN) v = ((const float4*)(X + (size_t)n * DD))[g];
        *(float4*)&Xs[row][g * 4] = v;
    }
    __syncthreads();
    const int to = tid & 31, tn = tid >> 5;
    float acc[8][4];
    #pragma unroll
    for (int k = 0; k < 8; ++k)
        #pragma unroll
        for (int j = 0; j < 4; ++j) acc[k][j] = 0.f;
    for (int i = 0; i < DD; ++i) {
        const float4 w = ((const float4*)(W0 + (size_t)i * DD))[to];
        #pragma unroll
        for (int k = 0; k < 8; ++k) {
            const float xs = Xs[tn * 8 + k][i];
            acc[k][0] += xs * w.x; acc[k][1] += xs * w.y;
            acc[k][2] += xs * w.z; acc[k][3] += xs * w.w;
        }
    }
    #pragma unroll
    for (int k = 0; k < 8; ++k) {
        const int n = n0 + tn * 8 + k;
        if (n < NN)
            ((float4*)(out + (size_t)n * DD))[to] =
                make_float4(acc[k][0], acc[k][1], acc[k][2], acc[k][3]);
    }
}

__global__ __launch_bounds__(128) void edge_fallback_kernel(
    const float* __restrict__ X, const float* __restrict__ W,
    const float* __restrict__ inv_norm,
    const int* __restrict__ src, const int* __restrict__ dst,
    const int* __restrict__ rel, float* __restrict__ out)
{
    const int o = threadIdx.x;
    for (int e = blockIdx.x; e < NE; e += gridDim.x) {
        const int s = src[e], d = dst[e], r = rel[e];
        const float inv = inv_norm[(size_t)d * NR + r];
        const float* Xr = X + (size_t)s * DD;
        const float* Wr = W + (size_t)r * DD * DD;
        float a = 0.f;
        for (int i = 0; i < DD; ++i) a += Xr[i] * Wr[i * DD + o];
        unsafeAtomicAdd(out + (size_t)d * DD + o, a * inv);
    }
}

// ---------------------------------------------------------------------------
extern "C" void kernel_launch(void* const* d_in, const int* in_sizes, int n_in,
                              void* d_out, int out_size, void* d_ws, size_t ws_size,
                              hipStream_t stream)
{
    const float* X        = (const float*)d_in[0];
    const float* W        = (const float*)d_in[1];
    const float* W0       = (const float*)d_in[2];
    const float* inv_norm = (const float*)d_in[3];
    const int*   src      = (const int*)d_in[4];
    const int*   dst      = (const int*)d_in[5];
    const int*   rel      = (const int*)d_in[6];
    float* out = (float*)d_out;

    // workspace layout
    char* ws = (char*)d_ws;
    size_t off = 0;
    auto alloc = [&](size_t bytes) {
        void* p = ws + off;
        off += (bytes + 255) & ~(size_t)255;
        return p;
    };
    __hip_bfloat16* A = (__hip_bfloat16*)alloc((size_t)NN * KTOT * sizeof(__hip_bfloat16));
    int*      offsets = (int*)alloc((size_t)(NN + 1) * sizeof(int));
    int*      cursor  = (int*)alloc((size_t)NN * sizeof(int));
    int*      cnt     = (int*)alloc((size_t)NN * sizeof(int));
    unsigned* packed  = (unsigned*)alloc((size_t)NE * sizeof(unsigned));

    if (ws_size >= off) {
        hipMemsetAsync(cnt, 0, (size_t)NN * sizeof(int), stream);
        hist_kernel<<<(NE + 255) / 256, 256, 0, stream>>>(dst, cnt);
        scan_kernel<<<1, 1024, 0, stream>>>(cnt, offsets, cursor);
        scatter_kernel<<<(NE + 255) / 256, 256, 0, stream>>>(src, dst, rel, cursor, packed);
        agg_kernel<<<(NN + 3) / 4, 256, 0, stream>>>(X, inv_norm, offsets, packed, A);
        gemm_kernel<<<(NN + 63) / 64, 256, 0, stream>>>(A, X, W, W0, out);
    } else {
        xform0_kernel<<<(NN + 63) / 64, 256, 0, stream>>>(X, W0, out);
        edge_fallback_kernel<<<8192, 128, 0, stream>>>(X, W, inv_norm, src, dst, rel, out);
    }
}